// Round 1
// baseline (46933.719 us; speedup 1.0000x reference)
//
#include <hip/hip_runtime.h>
#include <math.h>

#define L_SEQ 500
#define NBS   512
#define N     64      // state dim == obs dim
#define NI    32      // input dim
#define AUGW  132     // 64 (S) + 64 (HC/E) + 1 (innov/z) + 3 pad -> rows 16B aligned
#define PW    68      // P row stride (16B aligned rows)
#define HW    65      // H row stride (conflict-free column reads)
#define BW    33      // B row stride

// dynamic LDS float counts
#define SM_FLOATS (64*AUGW + 64*PW + 64*HW + 64*BW + 64 + 64 + 32 + 64 + 64 + 64)

__global__ __launch_bounds__(256, 2)
void akf_kernel(const float* __restrict__ ext,   // (500,512,32)
                const float* __restrict__ obs,   // (500,512,64)
                const float* __restrict__ mu0,   // (512,64)
                const float* __restrict__ sg0,   // (512,64)
                const float* __restrict__ lsg,   // (64)
                const float* __restrict__ Bm,    // (64,32)
                const float* __restrict__ Hm,    // (64,64)
                const float* __restrict__ ldl,   // (64)
                float* __restrict__ out_mu,      // (500,512,64)
                float* __restrict__ out_ls)      // (500,512,64)
{
    extern __shared__ float sm[];
    float* Aug = sm;                    // 64*132: cols 0..63 S, 64..127 HC/E, 128 z
    float* P   = Aug + 64*AUGW;         // 64*68
    float* Hs  = P   + 64*PW;           // 64*65
    float* Bs  = Hs  + 64*HW;           // 64*33
    float* mu  = Bs  + 64*BW;           // 64
    float* mup = mu  + 64;              // 64 (mu_pred; sigma0 temp at init)
    float* uvec= mup + 64;              // 32
    float* rk  = uvec+ 32;              // 64 (1/pivot)
    float* Qd  = rk  + 64;              // 64
    float* Rd  = Qd  + 64;              // 64

    const int b   = blockIdx.x;
    const int tid = threadIdx.x;
    const int tx  = tid & 15;
    const int ty  = tid >> 4;
    const int r0  = ty * 4;
    const int c0  = tx * 4;

    // ---------------- init ----------------
    if (tid < N) {
        int i = tid;
        float q = expf(lsg[i]); Qd[i] = q * q;
        float r = expf(ldl[i]); Rd[i] = r * r;
        float m0 = mu0[b*N + i];
        float s0 = sg0[b*N + i];
        mu[i]  = m0;
        mup[i] = s0;                       // temp: sigma0
        out_mu[(size_t)(0*NBS + b)*N + i] = m0;
        out_ls[(size_t)(0*NBS + b)*N + i] = logf(s0);
        Aug[i*AUGW + 129] = 0.f; Aug[i*AUGW + 130] = 0.f; Aug[i*AUGW + 131] = 0.f;
    }
    for (int e = tid; e < N*N; e += 256) {
        int i = e >> 6, j = e & 63;
        Hs[i*HW + j] = Hm[e];
    }
    for (int e = tid; e < N*NI; e += 256) {
        int i = e >> 5, j = e & 31;
        Bs[i*BW + j] = Bm[e];
    }
    __syncthreads();
    // P = diag(sigma0^2)
    #pragma unroll
    for (int dr = 0; dr < 4; ++dr) {
        int i = r0 + dr;
        #pragma unroll
        for (int dc = 0; dc < 4; ++dc) {
            int j = c0 + dc;
            float v = 0.f;
            if (i == j) { float s = mup[i]; v = s * s; }
            P[i*PW + j] = v;
        }
    }
    __syncthreads();

    // ---------------- time loop ----------------
    for (int s = 0; s < L_SEQ - 1; ++s) {
        // (a) stage u
        if (tid < NI) uvec[tid] = ext[(size_t)(s*NBS + b)*NI + tid];
        __syncthreads();
        // (b) mu_pred = mu + B u
        if (tid < N) {
            int i = tid;
            float acc = mu[i];
            #pragma unroll
            for (int k = 0; k < NI; ++k) acc += Bs[i*BW + k] * uvec[k];
            mup[i] = acc;
        }
        __syncthreads();
        // (c) innov = y - H mu_pred ; P -> P_pred (diag += Q)
        if (tid < N) {
            int i = tid;
            float acc = obs[(size_t)((s+1)*NBS + b)*N + i];
            for (int k = 0; k < N; ++k) acc -= Hs[i*HW + k] * mup[k];
            Aug[i*AUGW + 128] = acc;
            P[i*PW + i] += Qd[i];
        }
        __syncthreads();

        // (d) E = H * Ppred  -> Aug cols 64..127
        {
            float acc[4][4];
            #pragma unroll
            for (int a = 0; a < 4; ++a)
                #pragma unroll
                for (int c = 0; c < 4; ++c) acc[a][c] = 0.f;
            for (int k = 0; k < N; ++k) {
                float4 bv = *(const float4*)&P[k*PW + c0];
                #pragma unroll
                for (int dr = 0; dr < 4; ++dr) {
                    float av = Hs[(r0+dr)*HW + k];
                    acc[dr][0] += av * bv.x;
                    acc[dr][1] += av * bv.y;
                    acc[dr][2] += av * bv.z;
                    acc[dr][3] += av * bv.w;
                }
            }
            #pragma unroll
            for (int dr = 0; dr < 4; ++dr) {
                float4 v; v.x = acc[dr][0]; v.y = acc[dr][1]; v.z = acc[dr][2]; v.w = acc[dr][3];
                *(float4*)&Aug[(r0+dr)*AUGW + 64 + c0] = v;
            }
        }
        __syncthreads();

        // (e) S = E * H^T + R -> Aug cols 0..63
        {
            float acc[4][4];
            #pragma unroll
            for (int a = 0; a < 4; ++a)
                #pragma unroll
                for (int c = 0; c < 4; ++c) acc[a][c] = 0.f;
            for (int k = 0; k < N; ++k) {
                float a[4], bb[4];
                #pragma unroll
                for (int dr = 0; dr < 4; ++dr) a[dr]  = Aug[(r0+dr)*AUGW + 64 + k];
                #pragma unroll
                for (int dc = 0; dc < 4; ++dc) bb[dc] = Hs[(c0+dc)*HW + k];
                #pragma unroll
                for (int dr = 0; dr < 4; ++dr)
                    #pragma unroll
                    for (int dc = 0; dc < 4; ++dc)
                        acc[dr][dc] += a[dr] * bb[dc];
            }
            #pragma unroll
            for (int dr = 0; dr < 4; ++dr) {
                int i = r0 + dr;
                #pragma unroll
                for (int dc = 0; dc < 4; ++dc) {
                    if (i == c0 + dc) acc[dr][dc] += Rd[i];
                }
                float4 v; v.x = acc[dr][0]; v.y = acc[dr][1]; v.z = acc[dr][2]; v.w = acc[dr][3];
                *(float4*)&Aug[i*AUGW + c0] = v;
            }
        }
        __syncthreads();

        // (f) fused LDL^T forward elimination on [S | E | z], 1 sync per pivot
        for (int k = 0; k < N; ++k) {
            float piv = Aug[k*AUGW + k];
            float rkv = 1.0f / piv;
            if (tid == 0) rk[k] = rkv;
            float4 bL = *(const float4*)&Aug[k*AUGW + 4*tx];
            float4 bR = *(const float4*)&Aug[k*AUGW + 64 + 4*tx];
            float  zk = Aug[k*AUGW + 128];
            #pragma unroll
            for (int dr = 0; dr < 4; ++dr) {
                int i = r0 + dr;
                if (i > k) {
                    float coef = Aug[i*AUGW + k] * rkv;
                    int jb = 4 * tx;
                    if (jb + 3 > k) {
                        if (jb > k) {
                            float4 cv = *(const float4*)&Aug[i*AUGW + jb];
                            cv.x -= coef * bL.x; cv.y -= coef * bL.y;
                            cv.z -= coef * bL.z; cv.w -= coef * bL.w;
                            *(float4*)&Aug[i*AUGW + jb] = cv;
                        } else {
                            if (jb + 1 > k) Aug[i*AUGW + jb + 1] -= coef * bL.y;
                            if (jb + 2 > k) Aug[i*AUGW + jb + 2] -= coef * bL.z;
                            if (jb + 3 > k) Aug[i*AUGW + jb + 3] -= coef * bL.w;
                        }
                    }
                    {
                        float4 cv = *(const float4*)&Aug[i*AUGW + 64 + 4*tx];
                        cv.x -= coef * bR.x; cv.y -= coef * bR.y;
                        cv.z -= coef * bR.z; cv.w -= coef * bR.w;
                        *(float4*)&Aug[i*AUGW + 64 + 4*tx] = cv;
                    }
                    if (tx == 0) {
                        Aug[i*AUGW + 128] -= coef * zk;
                    }
                }
            }
            __syncthreads();
        }

        // (g) P_post = Ppred - E^T D^-1 E   (in place on P); mu update on wave 0
        {
            float4 pr[4];
            #pragma unroll
            for (int dr = 0; dr < 4; ++dr) pr[dr] = *(const float4*)&P[(r0+dr)*PW + c0];
            for (int k = 0; k < N; ++k) {
                float rkk = rk[k];
                float4 bv = *(const float4*)&Aug[k*AUGW + 64 + c0];
                float a[4];
                #pragma unroll
                for (int dr = 0; dr < 4; ++dr) a[dr] = Aug[k*AUGW + 64 + r0 + dr] * rkk;
                #pragma unroll
                for (int dr = 0; dr < 4; ++dr) {
                    pr[dr].x -= a[dr] * bv.x; pr[dr].y -= a[dr] * bv.y;
                    pr[dr].z -= a[dr] * bv.z; pr[dr].w -= a[dr] * bv.w;
                }
            }
            #pragma unroll
            for (int dr = 0; dr < 4; ++dr) *(float4*)&P[(r0+dr)*PW + c0] = pr[dr];
        }
        if (tid < N) {   // mu_post = mu_pred + E^T D^-1 z  (reads Aug/rk only)
            int i = tid;
            float acc = mup[i];
            for (int k = 0; k < N; ++k) {
                acc += Aug[k*AUGW + 64 + i] * (rk[k] * Aug[k*AUGW + 128]);
            }
            mu[i] = acc;
        }
        __syncthreads();

        // (h) outputs
        if (tid < N) {
            int i = tid;
            size_t o = (size_t)((s+1)*NBS + b)*N + i;
            out_mu[o] = mu[i];
            out_ls[o] = 0.5f * logf(P[i*PW + i]);
        }
        __syncthreads();
    }
}

extern "C" void kernel_launch(void* const* d_in, const int* in_sizes, int n_in,
                              void* d_out, int out_size, void* d_ws, size_t ws_size,
                              hipStream_t stream) {
    const float* ext = (const float*)d_in[0];
    const float* obs = (const float*)d_in[1];
    const float* mu0 = (const float*)d_in[2];
    const float* sg0 = (const float*)d_in[3];
    const float* lsg = (const float*)d_in[4];
    const float* Bm  = (const float*)d_in[5];
    const float* Hm  = (const float*)d_in[6];
    const float* ldl = (const float*)d_in[7];
    float* out_mu = (float*)d_out;
    float* out_ls = out_mu + (size_t)L_SEQ * NBS * N;

    size_t smem = (size_t)SM_FLOATS * sizeof(float);   // 77696 B
    // opt-in to >64KB dynamic LDS (160KB max on gfx950); idempotent, capture-safe
    hipFuncSetAttribute(reinterpret_cast<const void*>(akf_kernel),
                        hipFuncAttributeMaxDynamicSharedMemorySize, (int)smem);

    akf_kernel<<<dim3(NBS), dim3(256), smem, stream>>>(
        ext, obs, mu0, sg0, lsg, Bm, Hm, ldl, out_mu, out_ls);
}

// Round 2
// 18132.069 us; speedup vs baseline: 2.5884x; 2.5884x over previous
//
#include <hip/hip_runtime.h>
#include <math.h>

#define L_SEQ 500
#define NBS   512
#define N     64
#define NI    32
#define AUGW  132   // Aug row stride: cols 0..63 S(lower), 64..127 E, 128 z, 129..131 pad(0)
#define PW    68    // P row stride
#define HW    68    // H row stride

// LDS layout (floats); every array base and row stride is 16B aligned
#define OFF_AUG 0
#define OFF_P   (OFF_AUG + 64*AUGW)   //  8448
#define OFF_H   (OFF_P   + 64*PW)     // 12800
#define OFF_BT  (OFF_H   + 64*HW)     // 17152  (B transposed: Bt[k*64+i] = B[i][k])
#define OFF_RK  (OFF_BT  + NI*64)     // 19200
#define OFF_QD  (OFF_RK  + 64)
#define OFF_RD  (OFF_QD  + 64)
#define OFF_MU  (OFF_RD  + 64)
#define OFF_MUP (OFF_MU  + 64)
#define OFF_WV  (OFF_MUP + 64)
#define OFF_U   (OFF_WV  + 64)
#define SM_FLOATS (OFF_U + 32)        // 19616 floats = 78464 B -> 2 blocks/CU

union F4 { float4 v; float f[4]; };

// Lw (= L*D^{-1}-scaled panel, i.e. true L factors) overlaid in Aug's strict upper
// triangle: rows 0..47, cols 48..63 (never used by lower-only S math). Row i of Lw
// (i in [16,64)) lives at Aug[(i-16)*AUGW + 48 + k], k in [0,16).
#define LW(i,k) Aug[((i)-16)*AUGW + 48 + (k)]

__global__ __launch_bounds__(256, 2)
void akf2(const float* __restrict__ ext,   // (500,512,32)
          const float* __restrict__ obs,   // (500,512,64)
          const float* __restrict__ mu0,   // (512,64)
          const float* __restrict__ sg0,   // (512,64)
          const float* __restrict__ lsg,   // (64)
          const float* __restrict__ Bm,    // (64,32)
          const float* __restrict__ Hm,    // (64,64)
          const float* __restrict__ ldl,   // (64)
          float* __restrict__ out_mu,      // (500,512,64)
          float* __restrict__ out_ls)      // (500,512,64)
{
    extern __shared__ float sm[];
    float* Aug = sm + OFF_AUG;
    float* P   = sm + OFF_P;
    float* Hs  = sm + OFF_H;
    float* Bt  = sm + OFF_BT;
    float* rk  = sm + OFF_RK;
    float* Qd  = sm + OFF_QD;
    float* Rd  = sm + OFF_RD;
    float* mu  = sm + OFF_MU;
    float* mup = sm + OFF_MUP;
    float* wv  = sm + OFF_WV;
    float* uvec= sm + OFF_U;

    const int b   = blockIdx.x;
    const int tid = threadIdx.x;
    const int tx  = tid & 15;
    const int ty  = tid >> 4;

    // packed lower-incl-diag 16x16 tile map for tid<136 (used by phases e,g)
    int Rlow = 0, Clow = 0;
    {
        int t = tid < 136 ? tid : 0;
        int R = (int)((sqrtf(8.0f * (float)t + 1.0f) - 1.0f) * 0.5f);
        if ((R + 1) * (R + 2) / 2 <= t) ++R;
        if (R * (R + 1) / 2 > t) --R;
        Rlow = R; Clow = t - R * (R + 1) / 2;
    }
    // packed strictly-lower pair map for mirror threads (tid-64 in [0,120))
    int Rm2 = 1, Cm2 = 0;
    {
        int m = (tid >= 64 && tid < 184) ? (tid - 64) : 0;
        int R = (int)((sqrtf(8.0f * (float)m + 1.0f) + 1.0f) * 0.5f);
        if (R * (R - 1) / 2 > m) --R;
        if ((R + 1) * R / 2 <= m) ++R;
        if (R < 1) R = 1;
        Rm2 = R; Cm2 = m - R * (R - 1) / 2;
    }

    // ---------------- init ----------------
    if (tid < 64) {
        int i = tid;
        float q = expf(lsg[i]); Qd[i] = q * q;
        float r = expf(ldl[i]); Rd[i] = r * r;
        float m0 = mu0[b * N + i];
        float s0 = sg0[b * N + i];
        mu[i]  = m0;
        mup[i] = s0;                       // temp: sigma0
        out_mu[(size_t)b * N + i] = m0;
        out_ls[(size_t)b * N + i] = logf(s0);
        Aug[i * AUGW + 129] = 0.f; Aug[i * AUGW + 130] = 0.f; Aug[i * AUGW + 131] = 0.f;
    }
    for (int e = tid; e < N * N; e += 256) {
        Hs[(e >> 6) * HW + (e & 63)] = Hm[e];
    }
    for (int e = tid; e < N * NI; e += 256) {
        int i = e >> 5, k = e & 31;
        Bt[k * 64 + i] = Bm[e];
    }
    __syncthreads();
    for (int e = tid; e < N * N; e += 256) {
        int i = e >> 6, j = e & 63;
        float v = 0.f;
        if (i == j) { float s = mup[i]; v = s * s; }
        P[i * PW + j] = v;
    }
    if (tid >= 192 && tid < 200) {     // stage u for s=0
        int q = tid - 192;
        *(float4*)&uvec[4 * q] = *(const float4*)&ext[(size_t)b * NI + 4 * q];
    }
    __syncthreads();

    // ---------------- time loop ----------------
    #pragma unroll 1
    for (int s = 0; s < L_SEQ - 1; ++s) {
        // (b) mu_pred = mu + B u
        if (tid < 64) {
            float acc = mu[tid];
            #pragma unroll
            for (int k = 0; k < NI; ++k) acc += Bt[k * 64 + tid] * uvec[k];
            mup[tid] = acc;
        }
        __syncthreads();

        // (c) innov = y - H mu_pred ; P diag += Q
        if (tid < 64) {
            float acc = obs[(size_t)((s + 1) * NBS + b) * N + tid];
            #pragma unroll 4
            for (int c4 = 0; c4 < 16; ++c4) {
                F4 h; h.v = *(const float4*)&Hs[tid * HW + 4 * c4];
                F4 m; m.v = *(const float4*)&mup[4 * c4];
                acc -= h.f[0]*m.f[0] + h.f[1]*m.f[1] + h.f[2]*m.f[2] + h.f[3]*m.f[3];
            }
            Aug[tid * AUGW + 128] = acc;
            P[tid * PW + tid] += Qd[tid];
        }
        __syncthreads();

        // (d) E = H * Ppred  -> Aug cols 64..127 (P stored full-symmetric)
        {
            const int i0 = 4 * ty, j0 = 4 * tx;
            float acc[4][4];
            #pragma unroll
            for (int a = 0; a < 4; ++a)
                #pragma unroll
                for (int c = 0; c < 4; ++c) acc[a][c] = 0.f;
            #pragma unroll 4
            for (int c4 = 0; c4 < 16; ++c4) {
                F4 h4[4], p4[4];
                #pragma unroll
                for (int dr = 0; dr < 4; ++dr) h4[dr].v = *(const float4*)&Hs[(i0 + dr) * HW + 4 * c4];
                #pragma unroll
                for (int dk = 0; dk < 4; ++dk) p4[dk].v = *(const float4*)&P[(4 * c4 + dk) * PW + j0];
                #pragma unroll
                for (int dk = 0; dk < 4; ++dk)
                    #pragma unroll
                    for (int dr = 0; dr < 4; ++dr)
                        #pragma unroll
                        for (int dc = 0; dc < 4; ++dc)
                            acc[dr][dc] += h4[dr].f[dk] * p4[dk].f[dc];
            }
            #pragma unroll
            for (int dr = 0; dr < 4; ++dr) {
                float4 v; v.x = acc[dr][0]; v.y = acc[dr][1]; v.z = acc[dr][2]; v.w = acc[dr][3];
                *(float4*)&Aug[(i0 + dr) * AUGW + 64 + j0] = v;
            }
        }
        __syncthreads();

        // (e) S lower = E * H^T + R   (136 threads, lower-incl-diag tiles)
        if (tid < 136) {
            const int i0 = 4 * Rlow, j0 = 4 * Clow;
            float acc[4][4];
            #pragma unroll
            for (int a = 0; a < 4; ++a)
                #pragma unroll
                for (int c = 0; c < 4; ++c) acc[a][c] = 0.f;
            #pragma unroll 4
            for (int c4 = 0; c4 < 16; ++c4) {
                F4 a4[4], b4[4];
                #pragma unroll
                for (int dr = 0; dr < 4; ++dr) a4[dr].v = *(const float4*)&Aug[(i0 + dr) * AUGW + 64 + 4 * c4];
                #pragma unroll
                for (int dc = 0; dc < 4; ++dc) b4[dc].v = *(const float4*)&Hs[(j0 + dc) * HW + 4 * c4];
                #pragma unroll
                for (int dr = 0; dr < 4; ++dr)
                    #pragma unroll
                    for (int dc = 0; dc < 4; ++dc)
                        #pragma unroll
                        for (int dk = 0; dk < 4; ++dk)
                            acc[dr][dc] += a4[dr].f[dk] * b4[dc].f[dk];
            }
            #pragma unroll
            for (int dr = 0; dr < 4; ++dr) {
                #pragma unroll
                for (int dc = 0; dc < 4; ++dc)
                    if (i0 + dr == j0 + dc) acc[dr][dc] += Rd[i0 + dr];
                float4 v; v.x = acc[dr][0]; v.y = acc[dr][1]; v.z = acc[dr][2]; v.w = acc[dr][3];
                *(float4*)&Aug[(i0 + dr) * AUGW + j0] = v;
            }
        }
        __syncthreads();

        // (f) blocked LDL^T: 4 panels of 16 pivots
        #pragma unroll 1
        for (int p = 0; p < 4; ++p) {
            const int p0 = 16 * p;
            if (tid < 64) {
                // ---- F1: panel factor (wave 0, wave-synchronous, registers + shfl)
                const int lane = tid;
                float st[16], lw[16], myrk = 0.f;
                if (lane >= p0) {
                    #pragma unroll
                    for (int q = 0; q < 4; ++q) {
                        F4 t4; t4.v = *(const float4*)&Aug[lane * AUGW + p0 + 4 * q];
                        st[4*q+0] = t4.f[0]; st[4*q+1] = t4.f[1]; st[4*q+2] = t4.f[2]; st[4*q+3] = t4.f[3];
                    }
                } else {
                    #pragma unroll
                    for (int q = 0; q < 16; ++q) st[q] = 0.f;
                }
                #pragma unroll
                for (int kr = 0; kr < 16; ++kr) {
                    const int k = p0 + kr;
                    float dk  = __shfl(st[kr], k, 64);
                    float rkv = 1.0f / dk;
                    if (lane == k) myrk = rkv;
                    float coef = st[kr] * rkv;
                    coef = (lane > k) ? coef : 0.f;
                    lw[kr] = coef;
                    #pragma unroll
                    for (int jr = kr + 1; jr < 16; ++jr) {
                        float wjk = __shfl(st[kr], p0 + jr, 64);
                        st[jr] -= coef * wjk;
                    }
                }
                if (lane >= p0) {
                    #pragma unroll
                    for (int q = 0; q < 4; ++q) {
                        float4 v; v.x = st[4*q+0]; v.y = st[4*q+1]; v.z = st[4*q+2]; v.w = st[4*q+3];
                        *(float4*)&Aug[lane * AUGW + p0 + 4 * q] = v;   // W (raw factored)
                    }
                    if (lane < p0 + 16) rk[lane] = myrk;
                }
                if (lane >= 16) {
                    #pragma unroll
                    for (int q = 0; q < 4; ++q) {
                        float4 v; v.x = lw[4*q+0]; v.y = lw[4*q+1]; v.z = lw[4*q+2]; v.w = lw[4*q+3];
                        *(float4*)&LW(lane, 4 * q) = v;                 // true L factors
                    }
                }
                // ---- F2: panel-row E/z triangular update (same wave, register col-slices)
                float ec[16], zr[16];
                #pragma unroll
                for (int r2 = 0; r2 < 16; ++r2) {
                    ec[r2] = Aug[(p0 + r2) * AUGW + 64 + lane];
                    zr[r2] = Aug[(p0 + r2) * AUGW + 128];
                }
                #pragma unroll
                for (int kp = 0; kp < 15; ++kp) {
                    #pragma unroll
                    for (int r2 = kp + 1; r2 < 16; ++r2) {
                        float L = __shfl(lw[kp], p0 + r2, 64);
                        ec[r2] -= L * ec[kp];
                        zr[r2] -= L * zr[kp];
                    }
                }
                #pragma unroll
                for (int r2 = 0; r2 < 16; ++r2)
                    Aug[(p0 + r2) * AUGW + 64 + lane] = ec[r2];
                if (lane == 0) {
                    #pragma unroll
                    for (int r2 = 0; r2 < 16; ++r2)
                        Aug[(p0 + r2) * AUGW + 128] = zr[r2];
                }
            }
            __syncthreads();

            // ---- F3: rank-16 trailing update (S lower-trailing + E/z), GEMM-shaped
            {
                const int TS  = (p == 0) ? 78 : (p == 1) ? 36 : (p == 2) ? 10 : 0;
                const int rows = 48 - 16 * p;                 // trailing rows
                const int TE  = (rows > 0) ? (rows / 4) * 17 : 0;
                const int tot = TS + TE;
                const int ofs = 4 * (p + 1);
                #pragma unroll 1
                for (int t = tid; t < tot; t += 256) {
                    int i0, Cb; bool isS;
                    if (t < TS) {
                        int rr = (int)((sqrtf(8.0f * (float)t + 1.0f) - 1.0f) * 0.5f);
                        if ((rr + 1) * (rr + 2) / 2 <= t) ++rr;
                        if (rr * (rr + 1) / 2 > t) --rr;
                        int cc = t - rr * (rr + 1) / 2;
                        i0 = 4 * (ofs + rr); Cb = 4 * (ofs + cc); isS = true;
                    } else {
                        int e2 = t - TS;
                        i0 = 4 * (ofs + e2 / 17); Cb = 64 + 4 * (e2 % 17); isS = false;
                    }
                    F4 acc[4];
                    #pragma unroll
                    for (int dr = 0; dr < 4; ++dr) acc[dr].v = *(const float4*)&Aug[(i0 + dr) * AUGW + Cb];
                    #pragma unroll
                    for (int c4 = 0; c4 < 4; ++c4) {
                        F4 a4[4];
                        #pragma unroll
                        for (int dr = 0; dr < 4; ++dr) a4[dr].v = *(const float4*)&LW(i0 + dr, 4 * c4);
                        if (isS) {
                            F4 b4[4];
                            #pragma unroll
                            for (int dc = 0; dc < 4; ++dc) b4[dc].v = *(const float4*)&Aug[(Cb + dc) * AUGW + p0 + 4 * c4];
                            #pragma unroll
                            for (int dr = 0; dr < 4; ++dr)
                                #pragma unroll
                                for (int dc = 0; dc < 4; ++dc)
                                    #pragma unroll
                                    for (int dk = 0; dk < 4; ++dk)
                                        acc[dr].f[dc] -= a4[dr].f[dk] * b4[dc].f[dk];
                        } else {
                            F4 b4[4];
                            #pragma unroll
                            for (int dk = 0; dk < 4; ++dk) b4[dk].v = *(const float4*)&Aug[(p0 + 4 * c4 + dk) * AUGW + Cb];
                            #pragma unroll
                            for (int dk = 0; dk < 4; ++dk)
                                #pragma unroll
                                for (int dr = 0; dr < 4; ++dr)
                                    #pragma unroll
                                    for (int dc = 0; dc < 4; ++dc)
                                        acc[dr].f[dc] -= a4[dr].f[dk] * b4[dk].f[dc];
                        }
                    }
                    #pragma unroll
                    for (int dr = 0; dr < 4; ++dr) *(float4*)&Aug[(i0 + dr) * AUGW + Cb] = acc[dr].v;
                }
            }
            __syncthreads();
        }

        // (g) P_post lower = Ppred - E~^T D^-1 E~  (136 threads) ; mu on wave 3
        if (tid < 136) {
            const int i0 = 4 * Rlow, j0 = 4 * Clow;
            F4 acc[4];
            #pragma unroll
            for (int dr = 0; dr < 4; ++dr) acc[dr].v = *(const float4*)&P[(i0 + dr) * PW + j0];
            #pragma unroll 2
            for (int c4 = 0; c4 < 16; ++c4) {
                F4 rv; rv.v = *(const float4*)&rk[4 * c4];
                F4 ea[4], eb[4];
                #pragma unroll
                for (int dk = 0; dk < 4; ++dk) ea[dk].v = *(const float4*)&Aug[(4 * c4 + dk) * AUGW + 64 + i0];
                #pragma unroll
                for (int dk = 0; dk < 4; ++dk) eb[dk].v = *(const float4*)&Aug[(4 * c4 + dk) * AUGW + 64 + j0];
                #pragma unroll
                for (int dk = 0; dk < 4; ++dk) {
                    float sc[4];
                    #pragma unroll
                    for (int dr = 0; dr < 4; ++dr) sc[dr] = ea[dk].f[dr] * rv.f[dk];
                    #pragma unroll
                    for (int dr = 0; dr < 4; ++dr)
                        #pragma unroll
                        for (int dc = 0; dc < 4; ++dc)
                            acc[dr].f[dc] -= sc[dr] * eb[dk].f[dc];
                }
            }
            #pragma unroll
            for (int dr = 0; dr < 4; ++dr) *(float4*)&P[(i0 + dr) * PW + j0] = acc[dr].v;
        }
        if (tid >= 192) {   // mu_post = mu_pred + E~^T (rk .* z~)   (wave 3)
            const int i = tid - 192;
            wv[i] = rk[i] * Aug[i * AUGW + 128];
            float acc = mup[i];
            #pragma unroll 4
            for (int c4 = 0; c4 < 16; ++c4) {
                F4 wq; wq.v = *(const float4*)&wv[4 * c4];
                #pragma unroll
                for (int dk = 0; dk < 4; ++dk)
                    acc += Aug[(4 * c4 + dk) * AUGW + 64 + i] * wq.f[dk];
            }
            mu[i] = acc;
        }
        __syncthreads();

        // (h) outputs (wave 0) + P mirror (threads 64..183) + stage next u (wave 3)
        if (tid < 64) {
            size_t o = (size_t)((s + 1) * NBS + b) * N + tid;
            out_mu[o] = mu[tid];
            out_ls[o] = 0.5f * logf(P[tid * PW + tid]);
        }
        if (tid >= 64 && tid < 184) {   // mirror lower tile (Rm2,Cm2) -> upper
            const int i0 = 4 * Rm2, j0 = 4 * Cm2;
            F4 t4[4];
            #pragma unroll
            for (int dr = 0; dr < 4; ++dr) t4[dr].v = *(const float4*)&P[(i0 + dr) * PW + j0];
            #pragma unroll
            for (int dc = 0; dc < 4; ++dc) {
                float4 v; v.x = t4[0].f[dc]; v.y = t4[1].f[dc]; v.z = t4[2].f[dc]; v.w = t4[3].f[dc];
                *(float4*)&P[(j0 + dc) * PW + i0] = v;
            }
        }
        if (tid >= 192 && tid < 200) {
            int q = tid - 192;
            *(float4*)&uvec[4 * q] = *(const float4*)&ext[(size_t)((s + 1) * NBS + b) * NI + 4 * q];
        }
        __syncthreads();
    }
}

extern "C" void kernel_launch(void* const* d_in, const int* in_sizes, int n_in,
                              void* d_out, int out_size, void* d_ws, size_t ws_size,
                              hipStream_t stream) {
    const float* ext = (const float*)d_in[0];
    const float* obs = (const float*)d_in[1];
    const float* mu0 = (const float*)d_in[2];
    const float* sg0 = (const float*)d_in[3];
    const float* lsg = (const float*)d_in[4];
    const float* Bm  = (const float*)d_in[5];
    const float* Hm  = (const float*)d_in[6];
    const float* ldl = (const float*)d_in[7];
    float* out_mu = (float*)d_out;
    float* out_ls = out_mu + (size_t)L_SEQ * NBS * N;

    size_t smem = (size_t)SM_FLOATS * sizeof(float);   // 78464 B
    hipFuncSetAttribute(reinterpret_cast<const void*>(akf2),
                        hipFuncAttributeMaxDynamicSharedMemorySize, (int)smem);

    akf2<<<dim3(NBS), dim3(256), smem, stream>>>(
        ext, obs, mu0, sg0, lsg, Bm, Hm, ldl, out_mu, out_ls);
}